// Round 8
// baseline (1339.032 us; speedup 1.0000x reference)
//
#include <hip/hip_runtime.h>
#include <hip/hip_bf16.h>

#define N_NODES 131072
#define NGRAPH  256
#define NMAXN   512
#define NEDGE   1048576
#define FIN     128
#define HDIM    64
#define K1Q     128
#define EPB     1024           // edges per sort block
#define NBLK    (NEDGE / EPB)  // 1024 sort blocks

// -------------------- counting sort of edges by graph (atomic-free global) ----
__global__ __launch_bounds__(256) void k_hist2(const int* __restrict__ dst,
                                               int* __restrict__ h) {
    __shared__ int lh[NGRAPH];
    const int tid = threadIdx.x;
    lh[tid] = 0;
    __syncthreads();
    const int base = blockIdx.x * EPB;
#pragma unroll
    for (int j = 0; j < 4; ++j)
        atomicAdd(&lh[dst[base + j * 256 + tid] >> 9], 1);
    __syncthreads();
    h[blockIdx.x * 256 + tid] = lh[tid];
}

__global__ __launch_bounds__(256) void k_scan_bins(int* __restrict__ h,
                                                   int* __restrict__ binTot) {
    const int b = blockIdx.x;      // bin
    const int tid = threadIdx.x;   // handles blocks tid*4 .. tid*4+3
    int v[4], s = 0;
#pragma unroll
    for (int j = 0; j < 4; ++j) { v[j] = h[(tid * 4 + j) * 256 + b]; s += v[j]; }
    __shared__ int sc[256];
    sc[tid] = s;
    __syncthreads();
    for (int o = 1; o < 256; o <<= 1) {
        int t = (tid >= o) ? sc[tid - o] : 0;
        __syncthreads();
        sc[tid] += t;
        __syncthreads();
    }
    int run = sc[tid] - s;         // exclusive prefix of this thread's group
#pragma unroll
    for (int j = 0; j < 4; ++j) { int t = v[j]; h[(tid * 4 + j) * 256 + b] = run; run += t; }
    if (tid == 255) binTot[b] = sc[255];
}

__global__ __launch_bounds__(256) void k_binstart(const int* __restrict__ binTot,
                                                  int* __restrict__ starts) {
    const int tid = threadIdx.x;
    int v = binTot[tid];
    __shared__ int sc[256];
    sc[tid] = v;
    __syncthreads();
    for (int o = 1; o < 256; o <<= 1) {
        int t = (tid >= o) ? sc[tid - o] : 0;
        __syncthreads();
        sc[tid] += t;
        __syncthreads();
    }
    starts[tid] = sc[tid] - v;
    if (tid == 255) starts[256] = sc[255];
}

__global__ __launch_bounds__(256) void k_scatter2(const int* __restrict__ src,
                                                  const int* __restrict__ dst,
                                                  const int* __restrict__ h,
                                                  const int* __restrict__ starts,
                                                  int* __restrict__ epack) {
    __shared__ int base[NGRAPH];
    const int tid = threadIdx.x;
    base[tid] = h[blockIdx.x * 256 + tid] + starts[tid];
    __syncthreads();
    const int b0 = blockIdx.x * EPB;
#pragma unroll
    for (int j = 0; j < 4; ++j) {
        int e = b0 + j * 256 + tid;
        int d = dst[e];
        int pos = atomicAdd(&base[d >> 9], 1);
        epack[pos] = ((src[e] & (NMAXN - 1)) << 9) | (d & (NMAXN - 1));
    }
}

// within each graph, sort by dst-local -> CSR (rowptr + esrc)
__global__ __launch_bounds__(256) void k_sort_dst(
    const int* __restrict__ epack, const int* __restrict__ starts,
    int* __restrict__ esrc, int* __restrict__ rowptr)
{
    __shared__ int hist[NMAXN];
    __shared__ int excl[NMAXN];
    __shared__ int psc[256];
    const int g = blockIdx.x, tid = threadIdx.x;
    const int e0 = starts[g], e1 = starts[g + 1];
    hist[tid] = 0; hist[tid + 256] = 0;
    __syncthreads();
    for (int e = e0 + tid; e < e1; e += 256)
        atomicAdd(&hist[epack[e] & (NMAXN - 1)], 1);
    __syncthreads();
    int a = hist[2 * tid], b = hist[2 * tid + 1];
    psc[tid] = a + b;
    __syncthreads();
    for (int o = 1; o < 256; o <<= 1) {
        int t = (tid >= o) ? psc[tid - o] : 0;
        __syncthreads();
        psc[tid] += t;
        __syncthreads();
    }
    int ep = psc[tid] - a - b;     // exclusive pair prefix
    excl[2 * tid] = ep;
    excl[2 * tid + 1] = ep + a;
    __syncthreads();
    rowptr[g * NMAXN + 2 * tid]     = e0 + excl[2 * tid];
    rowptr[g * NMAXN + 2 * tid + 1] = e0 + excl[2 * tid + 1];
    if (g == NGRAPH - 1 && tid == 0) rowptr[N_NODES] = NEDGE;
    __syncthreads();
    for (int e = e0 + tid; e < e1; e += 256) {
        int p = epack[e];
        int d = p & (NMAXN - 1);
        int pos = e0 + atomicAdd(&excl[d], 1);
        esrc[pos] = p >> 9;
    }
}

__global__ void k_dinv2(const int* __restrict__ rowptr, float* __restrict__ d) {
    int i = blockIdx.x * blockDim.x + threadIdx.x;
    if (i < N_NODES) d[i] = rsqrtf((float)(rowptr[i + 1] - rowptr[i]) + 1.0f);
}

// ------------------------------------------------------------- generic GEMM
// (used for pool_lin1, Q projections, SAB/PMA2 projections)
template<int TM, int K, int CO, int MODE>
__global__ __launch_bounds__(256) void k_gemm(
    const float* __restrict__ A, int lda,
    const float* __restrict__ W, const float* __restrict__ bias,
    float* __restrict__ out, int ldo, int M)
{
    constexpr int WTS = K + 4;
    __shared__ float As[TM * K];
    __shared__ float Wt[CO * WTS];
    const int tid = threadIdx.x;
    const int row0 = blockIdx.x * TM;

    for (int i = tid; i < K * CO; i += 256) {
        int k = i / CO, c = i - k * CO;
        Wt[c * WTS + k] = W[i];
    }
    constexpr int VR = K / 4;
    for (int i = tid; i < TM * VR; i += 256) {
        int r = i / VR, v = i - r * VR;
        int gr = row0 + r;
        float4 val = make_float4(0.f, 0.f, 0.f, 0.f);
        if (gr < M) val = *(const float4*)(A + (size_t)gr * lda + v * 4);
        *(float4*)(As + r * K + v * 4) = val;
    }
    __syncthreads();

    constexpr int G = 256 / CO;
    constexpr int RPT = TM / G;
    const int co = tid % CO;
    const int g = tid / CO;

    float acc[RPT];
#pragma unroll
    for (int r = 0; r < RPT; ++r) acc[r] = 0.f;

    const float* wrow = Wt + co * WTS;
    for (int kk = 0; kk < K / 4; ++kk) {
        float4 w = *(const float4*)(wrow + kk * 4);
#pragma unroll
        for (int r = 0; r < RPT; ++r) {
            float4 a = *(const float4*)(As + (g * RPT + r) * K + kk * 4);
            acc[r] += a.x * w.x + a.y * w.y + a.z * w.z + a.w * w.w;
        }
    }
    float b = 0.f;
    if (MODE >= 1) b = bias[co];
#pragma unroll
    for (int r = 0; r < RPT; ++r) {
        int gr = row0 + g * RPT + r;
        if (gr < M) {
            float v = acc[r] + b;
            if (MODE == 2) v = fmaxf(v, 0.f);
            out[(size_t)gr * ldo + co] = v;
        }
    }
}

// ---------------- fused GCN conv: per-graph  T = A@Wslice  (LDS) + CSR aggregate
// out[n] = bias + dinv[n]*( Tl[n] + sum_{e in row n} Tl[src] ),  Tl = T*dinv.
// 32 output cols per launch. A,W,bias,out pre-offset to the column slice.
// LDS union: As chunk (32KB) + Wt live only before Tl (73.7KB) is written.
// NOTE: out must NOT alias any column range of A that later launches still read
// (round-7 bug: VD aliased XL; launch 4 read clobbered XL -> absmax 7.4e-2).
template<int K, int RELU>
__global__ __launch_bounds__(256) void k_gcn_fused(
    const float* __restrict__ A, int lda,
    const float* __restrict__ W, int ldw,
    const float* __restrict__ bias,
    const float* __restrict__ dinv,
    const int* __restrict__ esrc, const int* __restrict__ rowptr,
    float* __restrict__ out, int ldo)
{
    constexpr int C   = 8192 / K;      // chunk rows: K=128->64, 64->128, 32->256
    constexpr int NCH = NMAXN / C;
    constexpr int RPT = C / 8;         // rows per thread per chunk
    constexpr int LS  = 36;
    constexpr int WTS = K + 4;
    __shared__ float U[NMAXN * LS];    // 73728 B: Tl final; As=U[0..8192), Wt=U[8192..)
    __shared__ float dl[NMAXN];
    float* As = U;                     // 8192 floats (32 KB)
    float* Wt = U + 8192;              // 32*WTS <= 4224 floats
    const int g = blockIdx.x, tid = threadIdx.x;
    const int node0 = g * NMAXN;

    for (int i = tid; i < 32 * K; i += 256) {
        int k = i >> 5, co = i & 31;
        Wt[co * WTS + k] = W[k * ldw + co];
    }
    for (int i = tid; i < NMAXN; i += 256) dl[i] = dinv[node0 + i];

    const int co = tid & 31, grp = tid >> 5;   // 8 row groups
    float acc[64];
#pragma unroll
    for (int r = 0; r < 64; ++r) acc[r] = 0.f;

#pragma unroll
    for (int ch = 0; ch < NCH; ++ch) {
        __syncthreads();               // As reuse guard (also covers Wt/dl at ch=0)
        for (int i = tid; i < C * (K / 4); i += 256) {
            int r = i / (K / 4), v = i % (K / 4);
            *(float4*)(As + r * K + v * 4) =
                *(const float4*)(A + (size_t)(node0 + ch * C + r) * lda + v * 4);
        }
        __syncthreads();
        for (int kk = 0; kk < K / 4; ++kk) {
            float4 w = *(const float4*)(Wt + co * WTS + kk * 4);
#pragma unroll
            for (int r = 0; r < RPT; ++r) {
                float4 a = *(const float4*)(As + (grp * RPT + r) * K + kk * 4);
                acc[ch * RPT + r] += a.x * w.x + a.y * w.y + a.z * w.z + a.w * w.w;
            }
        }
    }
    __syncthreads();                    // all As/Wt reads done
    float* Tl = U;
#pragma unroll
    for (int ch = 0; ch < NCH; ++ch)
#pragma unroll
        for (int r = 0; r < RPT; ++r) {
            int row = ch * C + grp * RPT + r;
            Tl[row * LS + co] = acc[ch * RPT + r] * dl[row];
        }
    __syncthreads();
    // aggregate: 8 lanes share node n (broadcast reads)
    for (int i = tid; i < NMAXN * 8; i += 256) {
        int n = i >> 3, c4 = (i & 7) << 2;
        float4 s = *(const float4*)(Tl + n * LS + c4);
        const int eb = rowptr[node0 + n], ee = rowptr[node0 + n + 1];
        for (int e = eb; e < ee; ++e) {
            const float4 v = *(const float4*)(Tl + esrc[e] * LS + c4);
            s.x += v.x; s.y += v.y; s.z += v.z; s.w += v.w;
        }
        float wv = dl[n];
        float4 b4 = *(const float4*)(bias + c4);
        float4 o;
        o.x = b4.x + wv * s.x; o.y = b4.y + wv * s.y;
        o.z = b4.z + wv * s.z; o.w = b4.w + wv * s.w;
        if (RELU) {
            o.x = fmaxf(o.x, 0.f); o.y = fmaxf(o.y, 0.f);
            o.z = fmaxf(o.z, 0.f); o.w = fmaxf(o.w, 0.f);
        }
        *(float4*)(out + (size_t)(node0 + n) * ldo + c4) = o;
    }
}

// ---------------- attention: 2 queries/thread x 4 key-quarters, tiled softmax
// grid = NGRAPH*4 (graph, head); block = 256 = 64 q-slots x 4 quarters.
// Thread owns queries {qs, qs+64}; each K/V ds_read serves both (halves LDS issue).
// Defer-max rescale (THR=8). Partial (m,l,acc) merge via LDS (aliases Ks if it fits).
template<int NK, bool QSH>
__global__ __launch_bounds__(256) void k_attn(
    const float* __restrict__ Q, const float* __restrict__ K,
    const float* __restrict__ V, float* __restrict__ O)
{
    constexpr int KQ  = NK / 4;               // keys per quarter
    constexpr int MLF = 3 * 128 * 18;         // merge floats needed
    __shared__ float Ks[NK * 16];
    __shared__ float Vs[NK * 16];
    __shared__ float Mlsep[(NK * 16 >= MLF) ? 4 : MLF];
    float* Ml = (NK * 16 >= MLF) ? Ks : Mlsep;
    const int g = blockIdx.x >> 2;
    const int h = blockIdx.x & 3;
    const int tid = threadIdx.x;
    for (int i = tid; i < NK * 4; i += 256) {
        int k = i >> 2, dc = (i & 3) << 2;
        const size_t off = ((size_t)g * NK + k) * HDIM + h * 16 + dc;
        *(float4*)(Ks + k * 16 + dc) = *(const float4*)(K + off);
        *(float4*)(Vs + k * 16 + dc) = *(const float4*)(V + off);
    }
    __syncthreads();
    const int qs = tid & 63;                  // queries qs and qs+64
    const int quarter = tid >> 6;
    const int k0 = quarter * KQ;
    const float* qp0 = QSH ? (Q + (size_t)qs * HDIM + h * 16)
                           : (Q + ((size_t)g * K1Q + qs) * HDIM + h * 16);
    const float* qp1 = qp0 + 64 * HDIM;
    float qv0[16], qv1[16];
#pragma unroll
    for (int d = 0; d < 16; ++d) { qv0[d] = qp0[d]; qv1[d] = qp1[d]; }

    float m0 = -1e30f, l0 = 0.f, m1 = -1e30f, l1 = 0.f;
    float acc0[16], acc1[16];
#pragma unroll
    for (int d = 0; d < 16; ++d) { acc0[d] = 0.f; acc1[d] = 0.f; }

    for (int kt = 0; kt < KQ; kt += 8) {
        const int kb = k0 + kt;
        float s0[8], s1[8];
#pragma unroll
        for (int j = 0; j < 8; ++j) {
            float t0 = 0.f, t1 = 0.f;
#pragma unroll
            for (int d4 = 0; d4 < 4; ++d4) {
                float4 kv = *(const float4*)(Ks + (kb + j) * 16 + d4 * 4);
                t0 += qv0[d4*4] * kv.x + qv0[d4*4+1] * kv.y
                    + qv0[d4*4+2] * kv.z + qv0[d4*4+3] * kv.w;
                t1 += qv1[d4*4] * kv.x + qv1[d4*4+1] * kv.y
                    + qv1[d4*4+2] * kv.z + qv1[d4*4+3] * kv.w;
            }
            s0[j] = t0 * 0.125f; s1[j] = t1 * 0.125f;
        }
        float tm0 = fmaxf(fmaxf(fmaxf(s0[0], s0[1]), fmaxf(s0[2], s0[3])),
                          fmaxf(fmaxf(s0[4], s0[5]), fmaxf(s0[6], s0[7])));
        float tm1 = fmaxf(fmaxf(fmaxf(s1[0], s1[1]), fmaxf(s1[2], s1[3])),
                          fmaxf(fmaxf(s1[4], s1[5]), fmaxf(s1[6], s1[7])));
        if (tm0 > m0 + 8.f) {
            float cr = __expf(m0 - tm0);
            l0 *= cr;
#pragma unroll
            for (int d = 0; d < 16; ++d) acc0[d] *= cr;
            m0 = tm0;
        }
        if (tm1 > m1 + 8.f) {
            float cr = __expf(m1 - tm1);
            l1 *= cr;
#pragma unroll
            for (int d = 0; d < 16; ++d) acc1[d] *= cr;
            m1 = tm1;
        }
        float p0[8], p1[8];
#pragma unroll
        for (int j = 0; j < 8; ++j) {
            p0[j] = __expf(s0[j] - m0); l0 += p0[j];
            p1[j] = __expf(s1[j] - m1); l1 += p1[j];
        }
#pragma unroll
        for (int d4 = 0; d4 < 4; ++d4) {
#pragma unroll
            for (int j = 0; j < 8; ++j) {
                float4 v = *(const float4*)(Vs + (kb + j) * 16 + d4 * 4);
                acc0[d4*4]   += p0[j] * v.x;  acc1[d4*4]   += p1[j] * v.x;
                acc0[d4*4+1] += p0[j] * v.y;  acc1[d4*4+1] += p1[j] * v.y;
                acc0[d4*4+2] += p0[j] * v.z;  acc1[d4*4+2] += p1[j] * v.z;
                acc0[d4*4+3] += p0[j] * v.w;  acc1[d4*4+3] += p1[j] * v.w;
            }
        }
    }
    __syncthreads();                    // all Ks/Vs reads done (Ml may alias Ks)
    if (quarter) {
        float* w0 = Ml + ((quarter - 1) * 128 + qs) * 18;
        float* w1 = Ml + ((quarter - 1) * 128 + qs + 64) * 18;
        w0[0] = m0; w0[1] = l0;
        w1[0] = m1; w1[1] = l1;
#pragma unroll
        for (int d = 0; d < 16; ++d) { w0[2 + d] = acc0[d]; w1[2 + d] = acc1[d]; }
    }
    __syncthreads();
    if (quarter == 0) {
#pragma unroll
        for (int qq = 0; qq < 2; ++qq) {
            const int q = qs + qq * 64;
            float m = qq ? m1 : m0, l = qq ? l1 : l0;
            float ac[16];
#pragma unroll
            for (int d = 0; d < 16; ++d) ac[d] = qq ? acc1[d] : acc0[d];
            float M = m;
#pragma unroll
            for (int p = 0; p < 3; ++p) M = fmaxf(M, Ml[(p * 128 + q) * 18]);
            float c = __expf(m - M);
            float L = l * c;
#pragma unroll
            for (int d = 0; d < 16; ++d) ac[d] *= c;
#pragma unroll
            for (int p = 0; p < 3; ++p) {
                const float* r = Ml + (p * 128 + q) * 18;
                float cp = __expf(r[0] - M);
                L += r[1] * cp;
#pragma unroll
                for (int d = 0; d < 16; ++d) ac[d] += r[2 + d] * cp;
            }
            float inv = 1.f / L;
            float* op = O + ((size_t)g * K1Q + q) * HDIM + h * 16;
#pragma unroll
            for (int d = 0; d < 16; ++d) op[d] = ac[d] * inv;
        }
    }
}

// PMA2: 1 query, 128 keys. block = 256 = 4 graphs x 64 lanes (lane = h*16+d)
__global__ __launch_bounds__(256) void k_attn_pma2(
    const float* __restrict__ Q2p, const float* __restrict__ K3,
    const float* __restrict__ V3, float* __restrict__ O3)
{
    const int t = threadIdx.x;
    const int lane = t & 63;
    const int g = blockIdx.x * 4 + (t >> 6);
    const float q = Q2p[lane];
    const float* Kg = K3 + (size_t)g * 128 * HDIM + lane;
    const float* Vg = V3 + (size_t)g * 128 * HDIM + lane;
    float m = -1e30f, l = 0.f, acc = 0.f;
    for (int k = 0; k < 128; ++k) {
        float s = q * Kg[(size_t)k * HDIM];
        s += __shfl_xor(s, 1); s += __shfl_xor(s, 2);
        s += __shfl_xor(s, 4); s += __shfl_xor(s, 8);
        s *= 0.125f;
        float mn = fmaxf(m, s);
        float cr = __expf(m - mn), p = __expf(s - mn);
        l = l * cr + p;
        acc = acc * cr + p * Vg[(size_t)k * HDIM];
        m = mn;
    }
    O3[(size_t)g * HDIM + lane] = acc / l;
}

// -------------------------------------------- MAB epilogue: o = AO + Q ; out = o + relu(o@W + b)
template<int NQ>
__global__ __launch_bounds__(256) void k_mab_epi(
    const float* __restrict__ AO, const float* __restrict__ Qsrc,
    const float* __restrict__ W, const float* __restrict__ bias,
    float* __restrict__ out, int M)
{
    constexpr int TM = 128, KK = 64, CO = 64, WTS = KK + 4;
    __shared__ float Os[TM * KK];
    __shared__ float Wt[CO * WTS];
    const int tid = threadIdx.x;
    const int row0 = blockIdx.x * TM;
    for (int i = tid; i < KK * CO; i += 256) {
        int k = i >> 6, c = i & 63;
        Wt[c * WTS + k] = W[i];
    }
    for (int i = tid; i < TM * 16; i += 256) {
        int r = i >> 4, v = (i & 15) << 2;
        int gr = row0 + r;
        float4 a = make_float4(0.f, 0.f, 0.f, 0.f);
        if (gr < M) {
            float4 x = *(const float4*)(AO + (size_t)gr * KK + v);
            int qr = (NQ == 0) ? gr : (NQ == 1 ? 0 : (gr & (NQ - 1)));
            float4 qv = *(const float4*)(Qsrc + (size_t)qr * KK + v);
            a.x = x.x + qv.x; a.y = x.y + qv.y; a.z = x.z + qv.z; a.w = x.w + qv.w;
        }
        *(float4*)(Os + r * KK + v) = a;
    }
    __syncthreads();
    const int co = tid & 63, g = tid >> 6;
    float acc[32];
#pragma unroll
    for (int r = 0; r < 32; ++r) acc[r] = 0.f;
    const float* wrow = Wt + co * WTS;
    for (int kk = 0; kk < KK / 4; ++kk) {
        float4 w = *(const float4*)(wrow + kk * 4);
#pragma unroll
        for (int r = 0; r < 32; ++r) {
            float4 a = *(const float4*)(Os + (g * 32 + r) * KK + kk * 4);
            acc[r] += a.x * w.x + a.y * w.y + a.z * w.z + a.w * w.w;
        }
    }
    float b = bias[co];
#pragma unroll
    for (int r = 0; r < 32; ++r) {
        int gr = row0 + g * 32 + r;
        if (gr < M) {
            float o = Os[(g * 32 + r) * KK + co];
            out[(size_t)gr * CO + co] = o + fmaxf(acc[r] + b, 0.f);
        }
    }
}

// -------------------------------------------------------- final MLP head (f32 out)
__global__ __launch_bounds__(64) void k_head(
    const float* __restrict__ BX3,
    const float* __restrict__ W1, const float* __restrict__ b1,
    const float* __restrict__ W2, const float* __restrict__ b2,
    const float* __restrict__ W3, const float* __restrict__ b3,
    float* __restrict__ outp)
{
    __shared__ float w1[64 * 32], w2[32 * 16], w3[32], bb1[32], bb2[16], bb3[2];
    const int tid = threadIdx.x;
    for (int i = tid; i < 64 * 32; i += 64) w1[i] = W1[i];
    for (int i = tid; i < 32 * 16; i += 64) w2[i] = W2[i];
    if (tid < 32) { w3[tid] = W3[tid]; bb1[tid] = b1[tid]; }
    if (tid < 16) bb2[tid] = b2[tid];
    if (tid < 2)  bb3[tid] = b3[tid];
    __syncthreads();
    const int g = blockIdx.x * 64 + tid;
    float x[64];
#pragma unroll
    for (int v = 0; v < 16; ++v) {
        float4 t = *(const float4*)(BX3 + (size_t)g * 64 + v * 4);
        x[v*4] = t.x; x[v*4+1] = t.y; x[v*4+2] = t.z; x[v*4+3] = t.w;
    }
    float gv[32];
    for (int c = 0; c < 32; ++c) {
        float a = bb1[c];
        for (int k = 0; k < 64; ++k) a += x[k] * w1[k * 32 + c];
        gv[c] = a;
    }
    float h1[16];
    for (int c = 0; c < 16; ++c) {
        float a = bb2[c];
        for (int k = 0; k < 32; ++k) a += gv[k] * w2[k * 16 + c];
        h1[c] = fmaxf(a, 0.f);
    }
    float z0 = bb3[0], z1 = bb3[1];
    for (int k = 0; k < 16; ++k) { z0 += h1[k] * w3[k * 2]; z1 += h1[k] * w3[k * 2 + 1]; }
    float mm = fmaxf(z0, z1);
    float ls = mm + logf(__expf(z0 - mm) + __expf(z1 - mm));
    outp[g * 2]     = z0 - ls;
    outp[g * 2 + 1] = z1 - ls;
}

// =========================================================================
extern "C" void kernel_launch(void* const* d_in, const int* in_sizes, int n_in,
                              void* d_out, int out_size, void* d_ws, size_t ws_size,
                              hipStream_t stream) {
    const float* x0  = (const float*)d_in[0];
    const int*   ei  = (const int*)d_in[1];
    const float* c1W = (const float*)d_in[3];  const float* c1b = (const float*)d_in[4];
    const float* c2W = (const float*)d_in[5];  const float* c2b = (const float*)d_in[6];
    const float* c3W = (const float*)d_in[7];  const float* c3b = (const float*)d_in[8];
    const float* plW = (const float*)d_in[9];  const float* plb = (const float*)d_in[10];
    const float* S1  = (const float*)d_in[11];
    const float* p1Wq = (const float*)d_in[12]; const float* p1bq = (const float*)d_in[13];
    const float* p1Wk = (const float*)d_in[14]; const float* p1bk = (const float*)d_in[15];
    const float* p1Wv = (const float*)d_in[16]; const float* p1bv = (const float*)d_in[17];
    const float* p1Wo = (const float*)d_in[18]; const float* p1bo = (const float*)d_in[19];
    const float* sWq  = (const float*)d_in[20]; const float* sbq  = (const float*)d_in[21];
    const float* sWk  = (const float*)d_in[22]; const float* sbk  = (const float*)d_in[23];
    const float* sWv  = (const float*)d_in[24]; const float* sbv  = (const float*)d_in[25];
    const float* sWo  = (const float*)d_in[26]; const float* sbo  = (const float*)d_in[27];
    const float* p2Wq = (const float*)d_in[28]; const float* p2bq = (const float*)d_in[29];
    const float* p2Wk = (const float*)d_in[30]; const float* p2bk = (const float*)d_in[31];
    const float* p2Wv = (const float*)d_in[32]; const float* p2bv = (const float*)d_in[33];
    const float* p2Wo = (const float*)d_in[34]; const float* p2bo = (const float*)d_in[35];
    const float* S2   = (const float*)d_in[36];
    const float* pl2W = (const float*)d_in[37]; const float* pl2b = (const float*)d_in[38];
    const float* l1W  = (const float*)d_in[39]; const float* l1b  = (const float*)d_in[40];
    const float* l2W  = (const float*)d_in[41]; const float* l2b  = (const float*)d_in[42];

    const int* src = ei;
    const int* dst = ei + NEDGE;

    float* ws = (float*)d_ws;
    float* dinv = ws;                               // [N]
    size_t off = N_NODES;
    int* epack  = (int*)(ws + off); off += NEDGE;   // edges sorted by graph
    int* h      = (int*)(ws + off); off += NBLK * 256;
    int* binTot = (int*)(ws + off); off += 256;
    int* starts = (int*)(ws + off); off += 257;
    int* esrc   = (int*)(ws + off); off += NEDGE;   // CSR src-local, sorted by dst
    int* rowptr = (int*)(ws + off); off += N_NODES + 1;
    off = (off + 255) & ~(size_t)255;
    float* Qp  = ws + off; off += K1Q * HDIM;       // [128,64]
    float* Q2p = ws + off; off += HDIM;
    float* O3  = ws + off; off += NGRAPH * HDIM;
    float* BX3 = ws + off; off += NGRAPH * HDIM;
    off = (off + 1023) & ~(size_t)1023;
    float* P0 = ws + off;
    const size_t SL = (size_t)N_NODES * 32;         // one [N,32] slab
    float* XC  = P0 + 2 * SL;       // [N,96] concat x1|x2|x3 (2SL..5SL)
    float* XL  = P0 + 5 * SL;       // [N,64] (5SL..7SL)
    float* KD  = P0;                // [N,64] (0..2SL)
    float* VD  = P0 + 2 * SL;       // [N,64] (2SL..4SL) — XC dead; must NOT alias XL
    float* O1  = P0 + 4 * SL;               // [B,128,64] (4SL..4.5SL)
    float* BX1 = P0 + 4 * SL + SL / 2;      // [B,128,64] (4.5SL..5SL)
    float* Qs  = P0;                        // SAB phase reuses P0..P3
    float* Ks_ = P0 + SL / 2;
    float* Vs_ = P0 + SL;
    float* O2  = P0 + SL + SL / 2;
    float* BX2 = P0 + 2 * SL;
    float* K3  = P0 + 2 * SL + SL / 2;
    float* V3  = P0 + 3 * SL;

    // edge sort by graph, then by dst within graph -> CSR; dinv from degrees
    k_hist2<<<NBLK, 256, 0, stream>>>(dst, h);
    k_scan_bins<<<256, 256, 0, stream>>>(h, binTot);
    k_binstart<<<1, 256, 0, stream>>>(binTot, starts);
    k_scatter2<<<NBLK, 256, 0, stream>>>(src, dst, h, starts, epack);
    k_sort_dst<<<NGRAPH, 256, 0, stream>>>(epack, starts, esrc, rowptr);
    k_dinv2<<<512, 256, 0, stream>>>(rowptr, dinv);

    // fused conv1/2/3 -> XC (stride 96)
    k_gcn_fused<128, 1><<<NGRAPH, 256, 0, stream>>>(x0, FIN, c1W, 32, c1b, dinv, esrc, rowptr, XC, 96);
    k_gcn_fused<32, 1><<<NGRAPH, 256, 0, stream>>>(XC, 96, c2W, 32, c2b, dinv, esrc, rowptr, XC + 32, 96);
    k_gcn_fused<32, 1><<<NGRAPH, 256, 0, stream>>>(XC + 32, 96, c3W, 32, c3b, dinv, esrc, rowptr, XC + 64, 96);

    // xl = concat @ plW + plb
    k_gemm<64, 96, 64, 1><<<2048, 256, 0, stream>>>(XC, 96, plW, plb, XL, 64, N_NODES);

    // fused K/V GCN convs -> KD, VD (two 32-col slices each; VD disjoint from XL)
    k_gcn_fused<64, 0><<<NGRAPH, 256, 0, stream>>>(XL, 64, p1Wk, 64, p1bk, dinv, esrc, rowptr, KD, 64);
    k_gcn_fused<64, 0><<<NGRAPH, 256, 0, stream>>>(XL, 64, p1Wk + 32, 64, p1bk + 32, dinv, esrc, rowptr, KD + 32, 64);
    k_gcn_fused<64, 0><<<NGRAPH, 256, 0, stream>>>(XL, 64, p1Wv, 64, p1bv, dinv, esrc, rowptr, VD, 64);
    k_gcn_fused<64, 0><<<NGRAPH, 256, 0, stream>>>(XL, 64, p1Wv + 32, 64, p1bv + 32, dinv, esrc, rowptr, VD + 32, 64);

    // MAB1 (PMA with 128 seeds)
    k_gemm<128, 64, 64, 1><<<1, 256, 0, stream>>>(S1, 64, p1Wq, p1bq, Qp, 64, K1Q);
    k_attn<512, true><<<NGRAPH * 4, 256, 0, stream>>>(Qp, KD, VD, O1);
    k_mab_epi<128><<<256, 256, 0, stream>>>(O1, Qp, p1Wo, p1bo, BX1, NGRAPH * K1Q);

    // SAB
    k_gemm<128, 64, 64, 1><<<256, 256, 0, stream>>>(BX1, 64, sWq, sbq, Qs, 64, NGRAPH * K1Q);
    k_gemm<128, 64, 64, 1><<<256, 256, 0, stream>>>(BX1, 64, sWk, sbk, Ks_, 64, NGRAPH * K1Q);
    k_gemm<128, 64, 64, 1><<<256, 256, 0, stream>>>(BX1, 64, sWv, sbv, Vs_, 64, NGRAPH * K1Q);
    k_attn<128, false><<<NGRAPH * 4, 256, 0, stream>>>(Qs, Ks_, Vs_, O2);
    k_mab_epi<0><<<256, 256, 0, stream>>>(O2, Qs, sWo, sbo, BX2, NGRAPH * K1Q);

    // PMA2 (single seed)
    k_gemm<128, 64, 64, 1><<<256, 256, 0, stream>>>(BX2, 64, p2Wk, p2bk, K3, 64, NGRAPH * K1Q);
    k_gemm<128, 64, 64, 1><<<256, 256, 0, stream>>>(BX2, 64, p2Wv, p2bv, V3, 64, NGRAPH * K1Q);
    k_gemm<128, 64, 64, 1><<<1, 256, 0, stream>>>(S2, 64, p2Wq, p2bq, Q2p, 64, 1);
    k_attn_pma2<<<64, 256, 0, stream>>>(Q2p, K3, V3, O3);
    k_mab_epi<1><<<2, 256, 0, stream>>>(O3, Q2p, p2Wo, p2bo, BX3, NGRAPH);

    // head
    k_head<<<4, 64, 0, stream>>>(BX3, pl2W, pl2b, l1W, l1b, l2W, l2b,
                                 (float*)d_out);
}

// Round 11
// 1169.964 us; speedup vs baseline: 1.1445x; 1.1445x over previous
//
#include <hip/hip_runtime.h>
#include <hip/hip_bf16.h>

#define N_NODES 131072
#define NGRAPH  256
#define NMAXN   512
#define NEDGE   1048576
#define FIN     128
#define HDIM    64
#define K1Q     128
#define EPB     1024           // edges per sort block
#define NBLK    (NEDGE / EPB)  // 1024 sort blocks

// -------------------- counting sort of edges by graph (atomic-free global) ----
__global__ __launch_bounds__(256) void k_hist2(const int* __restrict__ dst,
                                               int* __restrict__ h) {
    __shared__ int lh[NGRAPH];
    const int tid = threadIdx.x;
    lh[tid] = 0;
    __syncthreads();
    const int base = blockIdx.x * EPB;
#pragma unroll
    for (int j = 0; j < 4; ++j)
        atomicAdd(&lh[dst[base + j * 256 + tid] >> 9], 1);
    __syncthreads();
    h[blockIdx.x * 256 + tid] = lh[tid];
}

__global__ __launch_bounds__(256) void k_scan_bins(int* __restrict__ h,
                                                   int* __restrict__ binTot) {
    const int b = blockIdx.x;      // bin
    const int tid = threadIdx.x;   // handles blocks tid*4 .. tid*4+3
    int v[4], s = 0;
#pragma unroll
    for (int j = 0; j < 4; ++j) { v[j] = h[(tid * 4 + j) * 256 + b]; s += v[j]; }
    __shared__ int sc[256];
    sc[tid] = s;
    __syncthreads();
    for (int o = 1; o < 256; o <<= 1) {
        int t = (tid >= o) ? sc[tid - o] : 0;
        __syncthreads();
        sc[tid] += t;
        __syncthreads();
    }
    int run = sc[tid] - s;         // exclusive prefix of this thread's group
#pragma unroll
    for (int j = 0; j < 4; ++j) { int t = v[j]; h[(tid * 4 + j) * 256 + b] = run; run += t; }
    if (tid == 255) binTot[b] = sc[255];
}

__global__ __launch_bounds__(256) void k_binstart(const int* __restrict__ binTot,
                                                  int* __restrict__ starts) {
    const int tid = threadIdx.x;
    int v = binTot[tid];
    __shared__ int sc[256];
    sc[tid] = v;
    __syncthreads();
    for (int o = 1; o < 256; o <<= 1) {
        int t = (tid >= o) ? sc[tid - o] : 0;
        __syncthreads();
        sc[tid] += t;
        __syncthreads();
    }
    starts[tid] = sc[tid] - v;
    if (tid == 255) starts[256] = sc[255];
}

__global__ __launch_bounds__(256) void k_scatter2(const int* __restrict__ src,
                                                  const int* __restrict__ dst,
                                                  const int* __restrict__ h,
                                                  const int* __restrict__ starts,
                                                  int* __restrict__ epack) {
    __shared__ int base[NGRAPH];
    const int tid = threadIdx.x;
    base[tid] = h[blockIdx.x * 256 + tid] + starts[tid];
    __syncthreads();
    const int b0 = blockIdx.x * EPB;
#pragma unroll
    for (int j = 0; j < 4; ++j) {
        int e = b0 + j * 256 + tid;
        int d = dst[e];
        int pos = atomicAdd(&base[d >> 9], 1);
        epack[pos] = ((src[e] & (NMAXN - 1)) << 9) | (d & (NMAXN - 1));
    }
}

// within each graph, sort by dst-local -> CSR (rowptr + esrc)
__global__ __launch_bounds__(256) void k_sort_dst(
    const int* __restrict__ epack, const int* __restrict__ starts,
    int* __restrict__ esrc, int* __restrict__ rowptr)
{
    __shared__ int hist[NMAXN];
    __shared__ int excl[NMAXN];
    __shared__ int psc[256];
    const int g = blockIdx.x, tid = threadIdx.x;
    const int e0 = starts[g], e1 = starts[g + 1];
    hist[tid] = 0; hist[tid + 256] = 0;
    __syncthreads();
    for (int e = e0 + tid; e < e1; e += 256)
        atomicAdd(&hist[epack[e] & (NMAXN - 1)], 1);
    __syncthreads();
    int a = hist[2 * tid], b = hist[2 * tid + 1];
    psc[tid] = a + b;
    __syncthreads();
    for (int o = 1; o < 256; o <<= 1) {
        int t = (tid >= o) ? psc[tid - o] : 0;
        __syncthreads();
        psc[tid] += t;
        __syncthreads();
    }
    int ep = psc[tid] - a - b;     // exclusive pair prefix
    excl[2 * tid] = ep;
    excl[2 * tid + 1] = ep + a;
    __syncthreads();
    rowptr[g * NMAXN + 2 * tid]     = e0 + excl[2 * tid];
    rowptr[g * NMAXN + 2 * tid + 1] = e0 + excl[2 * tid + 1];
    if (g == NGRAPH - 1 && tid == 0) rowptr[N_NODES] = NEDGE;
    __syncthreads();
    for (int e = e0 + tid; e < e1; e += 256) {
        int p = epack[e];
        int d = p & (NMAXN - 1);
        int pos = e0 + atomicAdd(&excl[d], 1);
        esrc[pos] = p >> 9;
    }
}

__global__ void k_dinv2(const int* __restrict__ rowptr, float* __restrict__ d) {
    int i = blockIdx.x * blockDim.x + threadIdx.x;
    if (i < N_NODES) d[i] = rsqrtf((float)(rowptr[i + 1] - rowptr[i]) + 1.0f);
}

// ------------------------------------------------------------- generic GEMM
// W float4 read from LDS inside the k-loop (NOT preloaded): register preload
// caused 256-VGPR spills (round-3); per-thread acc kept small (round-8 lesson:
// acc[64] in fused GCN -> 256 VGPR + 170MB scratch writes -> reverted to split).
template<int TM, int K, int CO, int MODE>
__global__ __launch_bounds__(256) void k_gemm(
    const float* __restrict__ A, int lda,
    const float* __restrict__ W, const float* __restrict__ bias,
    float* __restrict__ out, int ldo, int M)
{
    constexpr int WTS = K + 4;
    __shared__ float As[TM * K];
    __shared__ float Wt[CO * WTS];
    const int tid = threadIdx.x;
    const int row0 = blockIdx.x * TM;

    for (int i = tid; i < K * CO; i += 256) {
        int k = i / CO, c = i - k * CO;
        Wt[c * WTS + k] = W[i];
    }
    constexpr int VR = K / 4;
    for (int i = tid; i < TM * VR; i += 256) {
        int r = i / VR, v = i - r * VR;
        int gr = row0 + r;
        float4 val = make_float4(0.f, 0.f, 0.f, 0.f);
        if (gr < M) val = *(const float4*)(A + (size_t)gr * lda + v * 4);
        *(float4*)(As + r * K + v * 4) = val;
    }
    __syncthreads();

    constexpr int G = 256 / CO;
    constexpr int RPT = TM / G;
    const int co = tid % CO;
    const int g = tid / CO;

    float acc[RPT];
#pragma unroll
    for (int r = 0; r < RPT; ++r) acc[r] = 0.f;

    const float* wrow = Wt + co * WTS;
    for (int kk = 0; kk < K / 4; ++kk) {
        float4 w = *(const float4*)(wrow + kk * 4);
#pragma unroll
        for (int r = 0; r < RPT; ++r) {
            float4 a = *(const float4*)(As + (g * RPT + r) * K + kk * 4);
            acc[r] += a.x * w.x + a.y * w.y + a.z * w.z + a.w * w.w;
        }
    }
    float b = 0.f;
    if (MODE >= 1) b = bias[co];
#pragma unroll
    for (int r = 0; r < RPT; ++r) {
        int gr = row0 + g * RPT + r;
        if (gr < M) {
            float v = acc[r] + b;
            if (MODE == 2) v = fmaxf(v, 0.f);
            out[(size_t)gr * ldo + co] = v;
        }
    }
}

// --------------------------------------- GCN aggregation (CSR, atomic-free)
// out[n] = bias + dinv[n] * ( Tl[n] + sum_{e in row n} Tl[src_e] )
// where Tl[x] = T[x]*dinv[x] (premultiplied on LDS load). 32 columns per call.
template<int RELU>
__global__ __launch_bounds__(256) void k_gcn_agg2(
    const float* __restrict__ T, int ldt,
    const float* __restrict__ dinv, const float* __restrict__ bias,
    const int* __restrict__ esrc, const int* __restrict__ rowptr,
    float* __restrict__ out, int ldo)
{
    constexpr int LS = 36;                 // padded row stride (16B-aligned float4)
    __shared__ float Tl[NMAXN * LS];
    __shared__ float dl[NMAXN];
    const int g = blockIdx.x;
    const int tid = threadIdx.x;
    const int node0 = g * NMAXN;

    for (int i = tid; i < NMAXN; i += 256) dl[i] = dinv[node0 + i];
    __syncthreads();
    for (int i = tid; i < NMAXN * 8; i += 256) {
        int r = i >> 3, c4 = (i & 7) << 2;
        float4 v = *(const float4*)(T + (size_t)(node0 + r) * ldt + c4);
        float w = dl[r];
        v.x *= w; v.y *= w; v.z *= w; v.w *= w;
        *(float4*)(Tl + r * LS + c4) = v;
    }
    __syncthreads();
    // lanes 0-7 share node n (broadcast esrc reads, uniform run length)
    for (int i = tid; i < NMAXN * 8; i += 256) {
        int n = i >> 3, c4 = (i & 7) << 2;
        float4 acc = *(const float4*)(Tl + n * LS + c4);
        const int eb = rowptr[node0 + n], ee = rowptr[node0 + n + 1];
        for (int e = eb; e < ee; ++e) {
            int ls = esrc[e];
            const float4 v = *(const float4*)(Tl + ls * LS + c4);
            acc.x += v.x; acc.y += v.y; acc.z += v.z; acc.w += v.w;
        }
        float w = dl[n];
        float4 b4 = *(const float4*)(bias + c4);
        float4 o;
        o.x = b4.x + w * acc.x; o.y = b4.y + w * acc.y;
        o.z = b4.z + w * acc.z; o.w = b4.w + w * acc.w;
        if (RELU) {
            o.x = fmaxf(o.x, 0.f); o.y = fmaxf(o.y, 0.f);
            o.z = fmaxf(o.z, 0.f); o.w = fmaxf(o.w, 0.f);
        }
        *(float4*)(out + (size_t)(node0 + n) * ldo + c4) = o;
    }
}

// ---------------- attention: 2 queries/thread x 4 key-quarters, tiled softmax
// grid = NGRAPH*4 (graph, head); block = 256 = 64 q-slots x 4 quarters.
// Thread owns queries {qs, qs+64}; each K/V ds_read serves both (halves LDS issue).
// Defer-max rescale (THR=8). Partial (m,l,acc) merge via LDS (aliases Ks if it fits).
template<int NK, bool QSH>
__global__ __launch_bounds__(256) void k_attn(
    const float* __restrict__ Q, const float* __restrict__ K,
    const float* __restrict__ V, float* __restrict__ O)
{
    constexpr int KQ  = NK / 4;               // keys per quarter
    constexpr int MLF = 3 * 128 * 18;         // merge floats needed
    __shared__ float Ks[NK * 16];
    __shared__ float Vs[NK * 16];
    __shared__ float Mlsep[(NK * 16 >= MLF) ? 4 : MLF];
    float* Ml = (NK * 16 >= MLF) ? Ks : Mlsep;
    const int g = blockIdx.x >> 2;
    const int h = blockIdx.x & 3;
    const int tid = threadIdx.x;
    for (int i = tid; i < NK * 4; i += 256) {
        int k = i >> 2, dc = (i & 3) << 2;
        const size_t off = ((size_t)g * NK + k) * HDIM + h * 16 + dc;
        *(float4*)(Ks + k * 16 + dc) = *(const float4*)(K + off);
        *(float4*)(Vs + k * 16 + dc) = *(const float4*)(V + off);
    }
    __syncthreads();
    const int qs = tid & 63;                  // queries qs and qs+64
    const int quarter = tid >> 6;
    const int k0 = quarter * KQ;
    const float* qp0 = QSH ? (Q + (size_t)qs * HDIM + h * 16)
                           : (Q + ((size_t)g * K1Q + qs) * HDIM + h * 16);
    const float* qp1 = qp0 + 64 * HDIM;
    float qv0[16], qv1[16];
#pragma unroll
    for (int d = 0; d < 16; ++d) { qv0[d] = qp0[d]; qv1[d] = qp1[d]; }

    float m0 = -1e30f, l0 = 0.f, m1 = -1e30f, l1 = 0.f;
    float acc0[16], acc1[16];
#pragma unroll
    for (int d = 0; d < 16; ++d) { acc0[d] = 0.f; acc1[d] = 0.f; }

    for (int kt = 0; kt < KQ; kt += 8) {
        const int kb = k0 + kt;
        float s0[8], s1[8];
#pragma unroll
        for (int j = 0; j < 8; ++j) {
            float t0 = 0.f, t1 = 0.f;
#pragma unroll
            for (int d4 = 0; d4 < 4; ++d4) {
                float4 kv = *(const float4*)(Ks + (kb + j) * 16 + d4 * 4);
                t0 += qv0[d4*4] * kv.x + qv0[d4*4+1] * kv.y
                    + qv0[d4*4+2] * kv.z + qv0[d4*4+3] * kv.w;
                t1 += qv1[d4*4] * kv.x + qv1[d4*4+1] * kv.y
                    + qv1[d4*4+2] * kv.z + qv1[d4*4+3] * kv.w;
            }
            s0[j] = t0 * 0.125f; s1[j] = t1 * 0.125f;
        }
        float tm0 = fmaxf(fmaxf(fmaxf(s0[0], s0[1]), fmaxf(s0[2], s0[3])),
                          fmaxf(fmaxf(s0[4], s0[5]), fmaxf(s0[6], s0[7])));
        float tm1 = fmaxf(fmaxf(fmaxf(s1[0], s1[1]), fmaxf(s1[2], s1[3])),
                          fmaxf(fmaxf(s1[4], s1[5]), fmaxf(s1[6], s1[7])));
        if (tm0 > m0 + 8.f) {
            float cr = __expf(m0 - tm0);
            l0 *= cr;
#pragma unroll
            for (int d = 0; d < 16; ++d) acc0[d] *= cr;
            m0 = tm0;
        }
        if (tm1 > m1 + 8.f) {
            float cr = __expf(m1 - tm1);
            l1 *= cr;
#pragma unroll
            for (int d = 0; d < 16; ++d) acc1[d] *= cr;
            m1 = tm1;
        }
        float p0[8], p1[8];
#pragma unroll
        for (int j = 0; j < 8; ++j) {
            p0[j] = __expf(s0[j] - m0); l0 += p0[j];
            p1[j] = __expf(s1[j] - m1); l1 += p1[j];
        }
#pragma unroll
        for (int d4 = 0; d4 < 4; ++d4) {
#pragma unroll
            for (int j = 0; j < 8; ++j) {
                float4 v = *(const float4*)(Vs + (kb + j) * 16 + d4 * 4);
                acc0[d4*4]   += p0[j] * v.x;  acc1[d4*4]   += p1[j] * v.x;
                acc0[d4*4+1] += p0[j] * v.y;  acc1[d4*4+1] += p1[j] * v.y;
                acc0[d4*4+2] += p0[j] * v.z;  acc1[d4*4+2] += p1[j] * v.z;
                acc0[d4*4+3] += p0[j] * v.w;  acc1[d4*4+3] += p1[j] * v.w;
            }
        }
    }
    __syncthreads();                    // all Ks/Vs reads done (Ml may alias Ks)
    if (quarter) {
        float* w0 = Ml + ((quarter - 1) * 128 + qs) * 18;
        float* w1 = Ml + ((quarter - 1) * 128 + qs + 64) * 18;
        w0[0] = m0; w0[1] = l0;
        w1[0] = m1; w1[1] = l1;
#pragma unroll
        for (int d = 0; d < 16; ++d) { w0[2 + d] = acc0[d]; w1[2 + d] = acc1[d]; }
    }
    __syncthreads();
    if (quarter == 0) {
#pragma unroll
        for (int qq = 0; qq < 2; ++qq) {
            const int q = qs + qq * 64;
            float m = qq ? m1 : m0, l = qq ? l1 : l0;
            float ac[16];
#pragma unroll
            for (int d = 0; d < 16; ++d) ac[d] = qq ? acc1[d] : acc0[d];
            float M = m;
#pragma unroll
            for (int p = 0; p < 3; ++p) M = fmaxf(M, Ml[(p * 128 + q) * 18]);
            float c = __expf(m - M);
            float L = l * c;
#pragma unroll
            for (int d = 0; d < 16; ++d) ac[d] *= c;
#pragma unroll
            for (int p = 0; p < 3; ++p) {
                const float* r = Ml + (p * 128 + q) * 18;
                float cp = __expf(r[0] - M);
                L += r[1] * cp;
#pragma unroll
                for (int d = 0; d < 16; ++d) ac[d] += r[2 + d] * cp;
            }
            float inv = 1.f / L;
            float* op = O + ((size_t)g * K1Q + q) * HDIM + h * 16;
#pragma unroll
            for (int d = 0; d < 16; ++d) op[d] = ac[d] * inv;
        }
    }
}

// PMA2: 1 query, 128 keys. block = 256 = 4 graphs x 64 lanes (lane = h*16+d)
__global__ __launch_bounds__(256) void k_attn_pma2(
    const float* __restrict__ Q2p, const float* __restrict__ K3,
    const float* __restrict__ V3, float* __restrict__ O3)
{
    const int t = threadIdx.x;
    const int lane = t & 63;
    const int g = blockIdx.x * 4 + (t >> 6);
    const float q = Q2p[lane];
    const float* Kg = K3 + (size_t)g * 128 * HDIM + lane;
    const float* Vg = V3 + (size_t)g * 128 * HDIM + lane;
    float m = -1e30f, l = 0.f, acc = 0.f;
    for (int k = 0; k < 128; ++k) {
        float s = q * Kg[(size_t)k * HDIM];
        s += __shfl_xor(s, 1); s += __shfl_xor(s, 2);
        s += __shfl_xor(s, 4); s += __shfl_xor(s, 8);
        s *= 0.125f;
        float mn = fmaxf(m, s);
        float cr = __expf(m - mn), p = __expf(s - mn);
        l = l * cr + p;
        acc = acc * cr + p * Vg[(size_t)k * HDIM];
        m = mn;
    }
    O3[(size_t)g * HDIM + lane] = acc / l;
}

// -------------------------------------------- MAB epilogue: o = AO + Q ; out = o + relu(o@W + b)
template<int NQ>
__global__ __launch_bounds__(256) void k_mab_epi(
    const float* __restrict__ AO, const float* __restrict__ Qsrc,
    const float* __restrict__ W, const float* __restrict__ bias,
    float* __restrict__ out, int M)
{
    constexpr int TM = 128, KK = 64, CO = 64, WTS = KK + 4;
    __shared__ float Os[TM * KK];
    __shared__ float Wt[CO * WTS];
    const int tid = threadIdx.x;
    const int row0 = blockIdx.x * TM;
    for (int i = tid; i < KK * CO; i += 256) {
        int k = i >> 6, c = i & 63;
        Wt[c * WTS + k] = W[i];
    }
    for (int i = tid; i < TM * 16; i += 256) {
        int r = i >> 4, v = (i & 15) << 2;
        int gr = row0 + r;
        float4 a = make_float4(0.f, 0.f, 0.f, 0.f);
        if (gr < M) {
            float4 x = *(const float4*)(AO + (size_t)gr * KK + v);
            int qr = (NQ == 0) ? gr : (NQ == 1 ? 0 : (gr & (NQ - 1)));
            float4 qv = *(const float4*)(Qsrc + (size_t)qr * KK + v);
            a.x = x.x + qv.x; a.y = x.y + qv.y; a.z = x.z + qv.z; a.w = x.w + qv.w;
        }
        *(float4*)(Os + r * KK + v) = a;
    }
    __syncthreads();
    const int co = tid & 63, g = tid >> 6;
    float acc[32];
#pragma unroll
    for (int r = 0; r < 32; ++r) acc[r] = 0.f;
    const float* wrow = Wt + co * WTS;
    for (int kk = 0; kk < KK / 4; ++kk) {
        float4 w = *(const float4*)(wrow + kk * 4);
#pragma unroll
        for (int r = 0; r < 32; ++r) {
            float4 a = *(const float4*)(Os + (g * 32 + r) * KK + kk * 4);
            acc[r] += a.x * w.x + a.y * w.y + a.z * w.z + a.w * w.w;
        }
    }
    float b = bias[co];
#pragma unroll
    for (int r = 0; r < 32; ++r) {
        int gr = row0 + g * 32 + r;
        if (gr < M) {
            float o = Os[(g * 32 + r) * KK + co];
            out[(size_t)gr * CO + co] = o + fmaxf(acc[r] + b, 0.f);
        }
    }
}

// -------------------------------------------------------- final MLP head (f32 out)
__global__ __launch_bounds__(64) void k_head(
    const float* __restrict__ BX3,
    const float* __restrict__ W1, const float* __restrict__ b1,
    const float* __restrict__ W2, const float* __restrict__ b2,
    const float* __restrict__ W3, const float* __restrict__ b3,
    float* __restrict__ outp)
{
    __shared__ float w1[64 * 32], w2[32 * 16], w3[32], bb1[32], bb2[16], bb3[2];
    const int tid = threadIdx.x;
    for (int i = tid; i < 64 * 32; i += 64) w1[i] = W1[i];
    for (int i = tid; i < 32 * 16; i += 64) w2[i] = W2[i];
    if (tid < 32) { w3[tid] = W3[tid]; bb1[tid] = b1[tid]; }
    if (tid < 16) bb2[tid] = b2[tid];
    if (tid < 2)  bb3[tid] = b3[tid];
    __syncthreads();
    const int g = blockIdx.x * 64 + tid;
    float x[64];
#pragma unroll
    for (int v = 0; v < 16; ++v) {
        float4 t = *(const float4*)(BX3 + (size_t)g * 64 + v * 4);
        x[v*4] = t.x; x[v*4+1] = t.y; x[v*4+2] = t.z; x[v*4+3] = t.w;
    }
    float gv[32];
    for (int c = 0; c < 32; ++c) {
        float a = bb1[c];
        for (int k = 0; k < 64; ++k) a += x[k] * w1[k * 32 + c];
        gv[c] = a;
    }
    float h1[16];
    for (int c = 0; c < 16; ++c) {
        float a = bb2[c];
        for (int k = 0; k < 32; ++k) a += gv[k] * w2[k * 16 + c];
        h1[c] = fmaxf(a, 0.f);
    }
    float z0 = bb3[0], z1 = bb3[1];
    for (int k = 0; k < 16; ++k) { z0 += h1[k] * w3[k * 2]; z1 += h1[k] * w3[k * 2 + 1]; }
    float mm = fmaxf(z0, z1);
    float ls = mm + logf(__expf(z0 - mm) + __expf(z1 - mm));
    outp[g * 2]     = z0 - ls;
    outp[g * 2 + 1] = z1 - ls;
}

// =========================================================================
extern "C" void kernel_launch(void* const* d_in, const int* in_sizes, int n_in,
                              void* d_out, int out_size, void* d_ws, size_t ws_size,
                              hipStream_t stream) {
    const float* x0  = (const float*)d_in[0];
    const int*   ei  = (const int*)d_in[1];
    const float* c1W = (const float*)d_in[3];  const float* c1b = (const float*)d_in[4];
    const float* c2W = (const float*)d_in[5];  const float* c2b = (const float*)d_in[6];
    const float* c3W = (const float*)d_in[7];  const float* c3b = (const float*)d_in[8];
    const float* plW = (const float*)d_in[9];  const float* plb = (const float*)d_in[10];
    const float* S1  = (const float*)d_in[11];
    const float* p1Wq = (const float*)d_in[12]; const float* p1bq = (const float*)d_in[13];
    const float* p1Wk = (const float*)d_in[14]; const float* p1bk = (const float*)d_in[15];
    const float* p1Wv = (const float*)d_in[16]; const float* p1bv = (const float*)d_in[17];
    const float* p1Wo = (const float*)d_in[18]; const float* p1bo = (const float*)d_in[19];
    const float* sWq  = (const float*)d_in[20]; const float* sbq  = (const float*)d_in[21];
    const float* sWk  = (const float*)d_in[22]; const float* sbk  = (const float*)d_in[23];
    const float* sWv  = (const float*)d_in[24]; const float* sbv  = (const float*)d_in[25];
    const float* sWo  = (const float*)d_in[26]; const float* sbo  = (const float*)d_in[27];
    const float* p2Wq = (const float*)d_in[28]; const float* p2bq = (const float*)d_in[29];
    const float* p2Wk = (const float*)d_in[30]; const float* p2bk = (const float*)d_in[31];
    const float* p2Wv = (const float*)d_in[32]; const float* p2bv = (const float*)d_in[33];
    const float* p2Wo = (const float*)d_in[34]; const float* p2bo = (const float*)d_in[35];
    const float* S2   = (const float*)d_in[36];
    const float* pl2W = (const float*)d_in[37]; const float* pl2b = (const float*)d_in[38];
    const float* l1W  = (const float*)d_in[39]; const float* l1b  = (const float*)d_in[40];
    const float* l2W  = (const float*)d_in[41]; const float* l2b  = (const float*)d_in[42];

    const int* src = ei;
    const int* dst = ei + NEDGE;

    float* ws = (float*)d_ws;
    float* dinv = ws;                               // [N]
    size_t off = N_NODES;
    int* epack  = (int*)(ws + off); off += NEDGE;   // edges sorted by graph
    int* h      = (int*)(ws + off); off += NBLK * 256;
    int* binTot = (int*)(ws + off); off += 256;
    int* starts = (int*)(ws + off); off += 257;
    int* esrc   = (int*)(ws + off); off += NEDGE;   // CSR src-local, sorted by dst
    int* rowptr = (int*)(ws + off); off += N_NODES + 1;
    off = (off + 255) & ~(size_t)255;
    float* Qp  = ws + off; off += K1Q * HDIM;       // [128,64]
    float* Q2p = ws + off; off += HDIM;
    float* O3  = ws + off; off += NGRAPH * HDIM;
    float* BX3 = ws + off; off += NGRAPH * HDIM;
    off = (off + 1023) & ~(size_t)1023;
    float* P0 = ws + off;
    const size_t SL = (size_t)N_NODES * 32;         // one [N,32] slab
    float* T32 = P0;                // GEMM scratch [N,32]
    float* T64 = P0;                // GEMM scratch [N,64] (P0,P1)
    float* XC  = P0 + 2 * SL;       // [N,96] concat x1|x2|x3 (2SL..5SL)
    float* XL  = P0 + 5 * SL;       // [N,64] (5SL..7SL)
    float* KD  = P0 + 2 * SL;       // [N,64] (2SL..4SL)  - after XC dead
    float* VD  = P0 + 5 * SL;       // [N,64] (5SL..7SL)  - safe: XL fully consumed
                                    //   into T64 by k_gemm BEFORE agg2 writes VD
    float* O1  = P0 + 4 * SL;               // [B,128,64]
    float* BX1 = P0 + 4 * SL + SL / 2;      // [B,128,64]
    float* Qs  = P0;                        // SAB phase reuses P0..P3
    float* Ks_ = P0 + SL / 2;
    float* Vs_ = P0 + SL;
    float* O2  = P0 + SL + SL / 2;
    float* BX2 = P0 + 2 * SL;
    float* K3  = P0 + 2 * SL + SL / 2;
    float* V3  = P0 + 3 * SL;

    // edge sort by graph, then by dst within graph -> CSR; dinv from degrees
    k_hist2<<<NBLK, 256, 0, stream>>>(dst, h);
    k_scan_bins<<<256, 256, 0, stream>>>(h, binTot);
    k_binstart<<<1, 256, 0, stream>>>(binTot, starts);
    k_scatter2<<<NBLK, 256, 0, stream>>>(src, dst, h, starts, epack);
    k_sort_dst<<<NGRAPH, 256, 0, stream>>>(epack, starts, esrc, rowptr);
    k_dinv2<<<512, 256, 0, stream>>>(rowptr, dinv);

    // conv1/2/3 -> XC (stride 96): split GEMM + CSR aggregation (no spills)
    k_gemm<64, 128, 32, 0><<<2048, 256, 0, stream>>>(x0, FIN, c1W, nullptr, T32, 32, N_NODES);
    k_gcn_agg2<1><<<256, 256, 0, stream>>>(T32, 32, dinv, c1b, esrc, rowptr, XC, 96);
    k_gemm<128, 32, 32, 0><<<1024, 256, 0, stream>>>(XC, 96, c2W, nullptr, T32, 32, N_NODES);
    k_gcn_agg2<1><<<256, 256, 0, stream>>>(T32, 32, dinv, c2b, esrc, rowptr, XC + 32, 96);
    k_gemm<128, 32, 32, 0><<<1024, 256, 0, stream>>>(XC + 32, 96, c3W, nullptr, T32, 32, N_NODES);
    k_gcn_agg2<1><<<256, 256, 0, stream>>>(T32, 32, dinv, c3b, esrc, rowptr, XC + 64, 96);

    // xl = concat @ plW + plb
    k_gemm<64, 96, 64, 1><<<2048, 256, 0, stream>>>(XC, 96, plW, plb, XL, 64, N_NODES);

    // K/V GCN convs -> KD, VD
    k_gemm<128, 64, 64, 0><<<1024, 256, 0, stream>>>(XL, 64, p1Wk, nullptr, T64, 64, N_NODES);
    k_gcn_agg2<0><<<256, 256, 0, stream>>>(T64, 64, dinv, p1bk, esrc, rowptr, KD, 64);
    k_gcn_agg2<0><<<256, 256, 0, stream>>>(T64 + 32, 64, dinv, p1bk + 32, esrc, rowptr, KD + 32, 64);
    k_gemm<128, 64, 64, 0><<<1024, 256, 0, stream>>>(XL, 64, p1Wv, nullptr, T64, 64, N_NODES);
    k_gcn_agg2<0><<<256, 256, 0, stream>>>(T64, 64, dinv, p1bv, esrc, rowptr, VD, 64);
    k_gcn_agg2<0><<<256, 256, 0, stream>>>(T64 + 32, 64, dinv, p1bv + 32, esrc, rowptr, VD + 32, 64);

    // MAB1 (PMA with 128 seeds)
    k_gemm<128, 64, 64, 1><<<1, 256, 0, stream>>>(S1, 64, p1Wq, p1bq, Qp, 64, K1Q);
    k_attn<512, true><<<NGRAPH * 4, 256, 0, stream>>>(Qp, KD, VD, O1);
    k_mab_epi<128><<<256, 256, 0, stream>>>(O1, Qp, p1Wo, p1bo, BX1, NGRAPH * K1Q);

    // SAB
    k_gemm<128, 64, 64, 1><<<256, 256, 0, stream>>>(BX1, 64, sWq, sbq, Qs, 64, NGRAPH * K1Q);
    k_gemm<128, 64, 64, 1><<<256, 256, 0, stream>>>(BX1, 64, sWk, sbk, Ks_, 64, NGRAPH * K1Q);
    k_gemm<128, 64, 64, 1><<<256, 256, 0, stream>>>(BX1, 64, sWv, sbv, Vs_, 64, NGRAPH * K1Q);
    k_attn<128, false><<<NGRAPH * 4, 256, 0, stream>>>(Qs, Ks_, Vs_, O2);
    k_mab_epi<0><<<256, 256, 0, stream>>>(O2, Qs, sWo, sbo, BX2, NGRAPH * K1Q);

    // PMA2 (single seed)
    k_gemm<128, 64, 64, 1><<<256, 256, 0, stream>>>(BX2, 64, p2Wk, p2bk, K3, 64, NGRAPH * K1Q);
    k_gemm<128, 64, 64, 1><<<256, 256, 0, stream>>>(BX2, 64, p2Wv, p2bv, V3, 64, NGRAPH * K1Q);
    k_gemm<128, 64, 64, 1><<<1, 256, 0, stream>>>(S2, 64, p2Wq, p2bq, Q2p, 64, 1);
    k_attn_pma2<<<64, 256, 0, stream>>>(Q2p, K3, V3, O3);
    k_mab_epi<1><<<2, 256, 0, stream>>>(O3, Q2p, p2Wo, p2bo, BX3, NGRAPH);

    // head
    k_head<<<4, 64, 0, stream>>>(BX3, pl2W, pl2b, l1W, l1b, l2W, l2b,
                                 (float*)d_out);
}